// Round 14
// baseline (11253.971 us; speedup 1.0000x reference)
//
#include <hip/hip_runtime.h>

typedef __attribute__((ext_vector_type(8))) short short8;
typedef __attribute__((ext_vector_type(4))) float floatx4;
typedef __attribute__((ext_vector_type(4))) int intx4;

#define T_STEPS 512
// d_out is FP32: outputs[512][64][1024], ht[64][1024], ct[64][1024]
#define OUT_HT_OFF 33554432ull
#define OUT_CT_OFF 33619968ull

// ws: wxh bf16 [4096][1024] (8MiB) | wxl (8MiB) | hbuf u32 [2][65536] (512KiB) | bar (4KiB)
#define WXH_OFF  0ull
#define WXL_OFF  (8ull << 20)
#define HBUF_OFF (16ull << 20)
#define BAR_OFF  ((16ull << 20) + (512ull << 10))
#define WS_NEED  ((16ull << 20) + (512ull << 10) + 4096ull)

// bar u32 offsets: [xcd*32] per-XCD arrive (L2-local) | [256] XCD-arrival |
// [288] generation | [640+xcd*32] slot assignment

static __device__ __forceinline__ unsigned short bf16_rne(float f) {
    union { float f; unsigned int u; } v; v.f = f;
    return (unsigned short)((v.u + 0x7FFFu + ((v.u >> 16) & 1u)) >> 16);
}
static __device__ __forceinline__ float bf16f(unsigned short u) {
    union { unsigned int u; float f; } v; v.u = ((unsigned int)u) << 16;
    return v.f;
}

__global__ void ws_sentinel(float* out) { out[threadIdx.x] = 2.0f; }

// one-time: W fp32 [1024][4096] -> k-major bf16 hi/lo split [4096][1024]
__global__ void __launch_bounds__(256) wsplit(const float* __restrict__ W,
                                              unsigned short* __restrict__ wxh,
                                              unsigned short* __restrict__ wxl) {
    __shared__ float tile[64][65];
    const int tx = threadIdx.x & 63;
    const int ty = threadIdx.x >> 6;
    const int cb = blockIdx.x * 64;
    const int kb = blockIdx.y * 64;
    #pragma unroll
    for (int i = 0; i < 16; ++i) {
        int kl = i * 4 + ty;
        tile[kl][tx] = W[(size_t)(kb + kl) * 4096 + cb + tx];
    }
    __syncthreads();
    #pragma unroll
    for (int i = 0; i < 16; ++i) {
        int cl = i * 4 + ty;
        float v = tile[tx][cl];
        unsigned short hi = bf16_rne(v);
        unsigned short lo = bf16_rne(v - bf16f(hi));
        wxh[(size_t)(cb + cl) * 1024 + kb + tx] = hi;
        wxl[(size_t)(cb + cl) * 1024 + kb + tx] = lo;
    }
}

// pipelined device-coherent h load (non-atomic) + progressive unpack->LDS
#define HLOAD(dst, OFF) \
    asm volatile("global_load_dwordx4 %0, %1, off offset:" OFF " sc0 sc1" \
                 : "=v"(dst) : "v"(hp8) : "memory");
#define HSTAGE(q, ra, rb, WAITSTR) \
    asm volatile("s_waitcnt " WAITSTR ::: "memory"); \
    __builtin_amdgcn_sched_barrier(0); \
    { unsigned w0=(unsigned)(ra).x, w1=(unsigned)(ra).y, w2=(unsigned)(ra).z, w3=(unsigned)(ra).w; \
      unsigned v0=(unsigned)(rb).x, v1=(unsigned)(rb).y, v2=(unsigned)(rb).z, v3=(unsigned)(rb).w; \
      intx4 hh, ll; \
      hh.x=(int)((w0&0xffffu)|(w1<<16)); hh.y=(int)((w2&0xffffu)|(w3<<16)); \
      hh.z=(int)((v0&0xffffu)|(v1<<16)); hh.w=(int)((v2&0xffffu)|(v3<<16)); \
      ll.x=(int)((w0>>16)|(w1&0xffff0000u)); ll.y=(int)((w2>>16)|(w3&0xffff0000u)); \
      ll.z=(int)((v0>>16)|(v1&0xffff0000u)); ll.w=(int)((v2>>16)|(v3&0xffff0000u)); \
      *(intx4*)(AhH + (wr*8+(q))*1024 + lane*16) = hh; \
      *(intx4*)(AhL + (wr*8+(q))*1024 + lane*16) = ll; }

// persistent LSTM scan with wave specialization.
// 512 thr = 8 waves. Waves 0-3 (R): critical path only (h exchange + resident
// h.R MFMA + gates + grid barrier). Waves 4-7 (X): free-running zx[t'] =
// x[t'].W + b producer into a depth-2 LDS ring (per R/X pair flags).
__global__ void __launch_bounds__(512, 1) lstm_scan(
    const float* __restrict__ R,              // [1024][4096] fp32
    const float* __restrict__ bias,           // [4096] fp32
    const float* __restrict__ x,              // [512][64][1024] fp32
    const unsigned short* __restrict__ wxh,   // bf16 [4096][1024] k-major
    const unsigned short* __restrict__ wxl,
    unsigned* __restrict__ hbuf,              // u32 [2][65536] packed(hi|lo<<16)
    unsigned* __restrict__ bar,
    float* __restrict__ out)                  // fp32 (outputs | ht | ct)
{
    __shared__ __align__(16) char AhH[32768];   // h hi fragments (shared by R-waves)
    __shared__ __align__(16) char AhL[32768];   // h lo
    __shared__ float ring[2][4][256];           // zx ring [slot][pair][row*16+col]
    __shared__ float zex[4][16 * 17];           // per-R-wave gate exchange (padded)
    __shared__ unsigned prodf[4], consf[4];     // ring flags per pair
    __shared__ unsigned stgc, garr;             // staging mini-bar, grid-arrive
    __shared__ unsigned s_as[2];
    extern __shared__ char lds_pad[];           // dynamic pad -> 1 WG/CU

    const int tid  = threadIdx.x;
    const int lane = tid & 63;
    const int wave = tid >> 6;                  // 0..7
    const int wr   = wave & 3;                  // pair index
    const bool isR = wave < 4;

    if (tid == 0) {
        unsigned xcc;
        asm volatile("s_getreg_b32 %0, hwreg(HW_REG_XCC_ID)" : "=s"(xcc));
        xcc &= 7u;
        unsigned slot = __hip_atomic_fetch_add(bar + 640 + xcc * 32, 1u,
                            __ATOMIC_RELAXED, __HIP_MEMORY_SCOPE_AGENT);
        s_as[0] = xcc; s_as[1] = slot;
        lds_pad[0] = 0;
    }
    if (tid < 4) { prodf[tid] = 0; consf[tid] = 0; }
    if (tid == 4) { stgc = 0; garr = 0; }
    __syncthreads();                             // only full-block sync (init)
    const int xcd  = (int)s_as[0];
    const int slot = (int)(s_as[1] & 31u);
    const int rg   = slot >> 3;
    const int jg   = xcd * 8 + (slot & 7);       // XCD-local W/unit columns
    const int rowbase = rg * 16;

    const int c16  = lane & 15;
    const int kgrp = lane >> 4;
    const int mycol = (c16 >> 2) * 1024 + jg * 16 + wr * 4 + (c16 & 3);

    if (isR) {
        // ================= R-wave: recurrent critical path =================
        short8 rh[32], rl[32];
        #pragma unroll
        for (int kk = 0; kk < 32; ++kk) {
            int kb = kk * 32 + kgrp * 8;
            short8 h8, l8;
            #pragma unroll
            for (int j = 0; j < 8; ++j) {
                float v = R[(size_t)(kb + j) * 4096 + mycol];
                unsigned short hh = bf16_rne(v);
                h8[j] = (short)hh;
                l8[j] = (short)bf16_rne(v - bf16f(hh));
            }
            rh[kk] = h8; rl[kk] = l8;
        }

        const int rr = lane >> 2;                // consumer row 0..15
        const int uu = lane & 3;                 // consumer unit-in-wave
        const int gcol = jg * 16 + wr * 4 + uu;
        const size_t cidx = (size_t)(rowbase + rr) * 1024 + gcol;
        float c_state = 0.f;

        for (int t = 0; t < T_STEPS; ++t) {
            // ---- wait for zx[t] from paired X-wave; seed accumulators ----
            while (__hip_atomic_load(&prodf[wr], __ATOMIC_ACQUIRE,
                                     __HIP_MEMORY_SCOPE_WORKGROUP) < (unsigned)(t + 1))
                __builtin_amdgcn_s_sleep(1);
            floatx4 a0;
            #pragma unroll
            for (int i = 0; i < 4; ++i)
                a0[i] = ring[t & 1][wr][(kgrp * 4 + i) * 16 + c16];
            if (lane == 0)
                __hip_atomic_store(&consf[wr], (unsigned)(t + 1),
                                   __ATOMIC_RELEASE, __HIP_MEMORY_SCOPE_WORKGROUP);

            // ---- stage h chunks [wr*8, wr*8+8) (pipelined, counted waits) ----
            if (t > 0) {
                const char* hp8 = (const char*)(hbuf + (size_t)(t & 1) * 65536)
                                + (rowbase + c16) * 4096 + wr * 1024 + kgrp * 32;
                intx4 r0, r1, r2, r3, r4, r5, r6, r7;
                intx4 r8, r9, r10, r11, r12, r13, r14, r15;
                HLOAD(r0,  "0")   HLOAD(r1,  "16")
                HLOAD(r2,  "128") HLOAD(r3,  "144")
                HLOAD(r4,  "256") HLOAD(r5,  "272")
                HLOAD(r6,  "384") HLOAD(r7,  "400")
                HLOAD(r8,  "512") HLOAD(r9,  "528")
                HLOAD(r10, "640") HLOAD(r11, "656")
                HLOAD(r12, "768") HLOAD(r13, "784")
                HLOAD(r14, "896") HLOAD(r15, "912")
                HSTAGE(0, r0,  r1,  "vmcnt(14)")
                HSTAGE(1, r2,  r3,  "vmcnt(12)")
                HSTAGE(2, r4,  r5,  "vmcnt(10)")
                HSTAGE(3, r6,  r7,  "vmcnt(8)")
                HSTAGE(4, r8,  r9,  "vmcnt(6)")
                HSTAGE(5, r10, r11, "vmcnt(4)")
                HSTAGE(6, r12, r13, "vmcnt(2)")
                HSTAGE(7, r14, r15, "vmcnt(0)")
            } else {
                intx4 z4 = {0, 0, 0, 0};
                #pragma unroll
                for (int q = 0; q < 8; ++q) {
                    *(intx4*)(AhH + (wr * 8 + q) * 1024 + lane * 16) = z4;
                    *(intx4*)(AhL + (wr * 8 + q) * 1024 + lane * 16) = z4;
                }
            }
            // ---- mini-barrier among the 4 R-waves (LDS, no __syncthreads) ----
            if (lane == 0)
                __hip_atomic_fetch_add(&stgc, 1u, __ATOMIC_RELEASE,
                                       __HIP_MEMORY_SCOPE_WORKGROUP);
            while (__hip_atomic_load(&stgc, __ATOMIC_ACQUIRE,
                                     __HIP_MEMORY_SCOPE_WORKGROUP) < 4u * (t + 1))
                __builtin_amdgcn_s_sleep(1);

            // ---- h.R MFMA (R resident; acc seeded with zx[t]) ----
            floatx4 a1 = {0,0,0,0}, a2 = {0,0,0,0}, a3 = {0,0,0,0};
            #pragma unroll
            for (int kk = 0; kk < 32; ++kk) {
                short8 ahh = *(const short8*)(AhH + kk * 1024 + lane * 16);
                short8 ahl = *(const short8*)(AhL + kk * 1024 + lane * 16);
                a0 = __builtin_amdgcn_mfma_f32_16x16x32_bf16(ahh, rh[kk], a0, 0, 0, 0);
                a1 = __builtin_amdgcn_mfma_f32_16x16x32_bf16(ahh, rl[kk], a1, 0, 0, 0);
                a2 = __builtin_amdgcn_mfma_f32_16x16x32_bf16(ahl, rh[kk], a2, 0, 0, 0);
                a3 = __builtin_amdgcn_mfma_f32_16x16x32_bf16(ahl, rl[kk], a3, 0, 0, 0);
            }

            // ---- in-wave z exchange (no cross-wave barrier needed) ----
            #pragma unroll
            for (int i = 0; i < 4; ++i)
                zex[wr][(kgrp * 4 + i) * 17 + c16] = (a0[i] + a1[i]) + (a2[i] + a3[i]);
            asm volatile("s_waitcnt lgkmcnt(0)" ::: "memory");
            __builtin_amdgcn_sched_barrier(0);
            float zi = zex[wr][rr * 17 +  0 + uu];
            float zf = zex[wr][rr * 17 +  4 + uu];
            float zc = zex[wr][rr * 17 +  8 + uu];
            float zo = zex[wr][rr * 17 + 12 + uu];

            float ig = 1.0f / (1.0f + expf(-zi));
            float fg = 1.0f / (1.0f + expf(-zf));
            float og = 1.0f / (1.0f + expf(-zo));
            float cc = tanhf(zc);
            float cn = fg * c_state + ig * cc;
            c_state = cn;
            float hval = og * tanhf(cn);

            out[(size_t)t * 65536 + cidx] = hval;
            if (t + 1 < T_STEPS) {
                unsigned short hi = bf16_rne(hval);
                unsigned short lo = bf16_rne(hval - bf16f(hi));
                unsigned w = (unsigned)hi | ((unsigned)lo << 16);
                unsigned* dst = hbuf + (size_t)((t + 1) & 1) * 65536 + cidx;
                asm volatile("global_store_dword %0, %1, off sc0 sc1"
                             :: "v"(dst), "v"(w) : "memory");
                asm volatile("s_waitcnt vmcnt(0)" ::: "memory");  // h at MALL

                // ---- grid barrier: WG-local gather then global chain ----
                if (lane == 0) {
                    unsigned s = (unsigned)(t + 1);
                    unsigned old = __hip_atomic_fetch_add(&garr, 1u,
                                       __ATOMIC_RELAXED, __HIP_MEMORY_SCOPE_WORKGROUP);
                    if (old == 4u * s - 1u) {            // last R-wave of WG
                        unsigned o2 = __hip_atomic_fetch_add(bar + xcd * 32, 1u,
                                          __ATOMIC_RELAXED, __HIP_MEMORY_SCOPE_WORKGROUP);
                        if (o2 == s * 32u - 1u) {        // last WG of XCD
                            unsigned og2 = __hip_atomic_fetch_add(bar + 256, 1u,
                                               __ATOMIC_RELAXED, __HIP_MEMORY_SCOPE_AGENT);
                            if (og2 == s * 8u - 1u)      // last XCD
                                __hip_atomic_store(bar + 288, s,
                                    __ATOMIC_RELAXED, __HIP_MEMORY_SCOPE_AGENT);
                        }
                    }
                }
                while (__hip_atomic_load(bar + 288, __ATOMIC_RELAXED,
                                         __HIP_MEMORY_SCOPE_AGENT) < (unsigned)(t + 1))
                    __builtin_amdgcn_s_sleep(2);
            } else {
                out[OUT_HT_OFF + cidx] = hval;
                out[OUT_CT_OFF + cidx] = cn;
            }
        }
    } else {
        // ================= X-wave: free-running zx producer =================
        const float biasreg = bias[mycol];
        const unsigned short* bph = wxh + (size_t)mycol * 1024 + kgrp * 8;
        const unsigned short* bpl = wxl + (size_t)mycol * 1024 + kgrp * 8;

        for (int tp = 0; tp < T_STEPS; ++tp) {
            // backpressure: slot tp&1 free once cons >= tp-1
            while ((int)__hip_atomic_load(&consf[wr], __ATOMIC_ACQUIRE,
                                          __HIP_MEMORY_SCOPE_WORKGROUP) < tp - 1)
                __builtin_amdgcn_s_sleep(2);

            const float* xb = x + (size_t)tp * 65536
                              + (size_t)(rowbase + c16) * 1024 + kgrp * 8;
            floatx4 b0 = {0,0,0,0}, b1 = {0,0,0,0}, b2 = {0,0,0,0}, b3 = {0,0,0,0};

            intx4  wb[2][8];
            floatx4 xv[2][8];
            #pragma unroll
            for (int j = 0; j < 4; ++j) {
                wb[0][2*j]   = *(const intx4*)(bph + j * 32);
                wb[0][2*j+1] = *(const intx4*)(bpl + j * 32);
                xv[0][2*j]   = *(const floatx4*)(xb + j * 32);
                xv[0][2*j+1] = *(const floatx4*)(xb + j * 32 + 4);
            }
            #pragma unroll
            for (int b = 0; b < 8; ++b) {
                const int cur = b & 1, nxt = cur ^ 1;
                if (b < 7) {
                    #pragma unroll
                    for (int j = 0; j < 4; ++j) {
                        int kk = (b + 1) * 4 + j;
                        wb[nxt][2*j]   = *(const intx4*)(bph + kk * 32);
                        wb[nxt][2*j+1] = *(const intx4*)(bpl + kk * 32);
                        xv[nxt][2*j]   = *(const floatx4*)(xb + kk * 32);
                        xv[nxt][2*j+1] = *(const floatx4*)(xb + kk * 32 + 4);
                    }
                }
                #pragma unroll
                for (int j = 0; j < 4; ++j) {
                    floatx4 f0 = xv[cur][2*j], f1 = xv[cur][2*j+1];
                    short8 axh, axl;
                    #pragma unroll
                    for (int e = 0; e < 4; ++e) {
                        unsigned short q0 = bf16_rne(f0[e]);
                        unsigned short q1 = bf16_rne(f1[e]);
                        axh[e]     = (short)q0;
                        axh[e + 4] = (short)q1;
                        axl[e]     = (short)bf16_rne(f0[e] - bf16f(q0));
                        axl[e + 4] = (short)bf16_rne(f1[e] - bf16f(q1));
                    }
                    short8 bxh = *(short8*)&wb[cur][2*j];
                    short8 bxl = *(short8*)&wb[cur][2*j+1];
                    b0 = __builtin_amdgcn_mfma_f32_16x16x32_bf16(axh, bxh, b0, 0, 0, 0);
                    b1 = __builtin_amdgcn_mfma_f32_16x16x32_bf16(axh, bxl, b1, 0, 0, 0);
                    b2 = __builtin_amdgcn_mfma_f32_16x16x32_bf16(axl, bxh, b2, 0, 0, 0);
                    b3 = __builtin_amdgcn_mfma_f32_16x16x32_bf16(axl, bxl, b3, 0, 0, 0);
                }
            }
            #pragma unroll
            for (int i = 0; i < 4; ++i)
                ring[tp & 1][wr][(kgrp * 4 + i) * 16 + c16] =
                    ((b0[i] + b1[i]) + (b2[i] + b3[i])) + biasreg;
            if (lane == 0)
                __hip_atomic_store(&prodf[wr], (unsigned)(tp + 1),
                                   __ATOMIC_RELEASE, __HIP_MEMORY_SCOPE_WORKGROUP);
        }
    }
}

extern "C" void kernel_launch(void* const* d_in, const int* in_sizes, int n_in,
                              void* d_out, int out_size, void* d_ws, size_t ws_size,
                              hipStream_t stream) {
    const float* inputs = (const float*)d_in[0];
    const float* W      = (const float*)d_in[1];
    const float* R      = (const float*)d_in[2];
    const float* bias   = (const float*)d_in[3];
    float* out = (float*)d_out;

    if (ws_size < WS_NEED) {
        ws_sentinel<<<1, 64, 0, stream>>>(out);
        return;
    }

    unsigned short* wxh  = (unsigned short*)((char*)d_ws + WXH_OFF);
    unsigned short* wxl  = (unsigned short*)((char*)d_ws + WXL_OFF);
    unsigned*       hbuf = (unsigned*)((char*)d_ws + HBUF_OFF);
    unsigned*       bar  = (unsigned*)((char*)d_ws + BAR_OFF);

    hipMemsetAsync(bar, 0, 4096, stream);
    wsplit<<<dim3(64, 16), 256, 0, stream>>>(W, wxh, wxl);
    // 16 KiB dynamic LDS pad: static (~77 KiB) + pad > 80 KiB -> 1 WG/CU
    lstm_scan<<<256, 512, 16384, stream>>>(R, bias, inputs, wxh, wxl, hbuf, bar, out);
}